// Round 17
// baseline (55.970 us; speedup 1.0000x reference)
//
#include <hip/hip_runtime.h>

#define HH 512
#define WW 1024
#define HWSZ (HH*WW)
#define NCLS 19
#define KEEP 128
#define CTHR 0.1f
#define NBLK 512            // nms tiles = (WW/64)*(HH/16)
#define NRED 16
#define SEGPB 32
#define GSLOT 192
#define GRID2 1024          // fused launch: all-resident (4 blocks/CU x 256 CU)
#define TAGMAGIC 0x5A17EC0Du
typedef unsigned int u32;
typedef unsigned long long u64;

// monotone value->bin map, 2048 bins, fine where the data lives (v in [0.5,1))
static __device__ __forceinline__ int key_bin2k(u64 k) {
    unsigned u = (unsigned)(k >> 32);
    if (u >= 0x3F000000u) {
        int b = 1024 + (int)((u - 0x3F000000u) >> 13);
        return b > 2047 ? 2047 : b;
    }
    return (int)(u >> 21);   // < 504
}

// wave-aggregated LDS push; call sites must be wave-uniform
static __device__ __forceinline__ int lds_push(int* cnt, bool want, int lane, u64 lmask_lt) {
    u64 mask = __ballot(want);
    int pos = -1;
    if (mask) {
        int leader = __builtin_ctzll(mask);
        int bpos = 0;
        if (lane == leader) bpos = atomicAdd(cnt, (int)__popcll(mask));
        bpos = __shfl(bpos, leader);
        if (want) pos = bpos + (int)__popcll(mask & lmask_lt);
    }
    return pos;
}

static __device__ __forceinline__ void bitonic_lds(u64* b, int m, int tid) {
    for (int kk = 2; kk <= m; kk <<= 1) {
        for (int j = kk >> 1; j; j >>= 1) {
            for (int i = tid; i < m; i += 256) {
                int ixj = i ^ j;
                if (ixj > i) {
                    bool desc = ((i & kk) == 0);
                    u64 a = b[i], c = b[ixj];
                    if ((a < c) == desc) { b[i] = c; b[ixj] = a; }
                }
            }
            __syncthreads();
        }
    }
}

// 256-elem descending bitonic, 1 elem/thread: shfl for j<64, LDS for j>=64
static __device__ __forceinline__ void bitonic256_reg(u64* ov, int tid) {
    u64 a = ov[tid];
    __syncthreads();
    for (int kk = 2; kk <= 256; kk <<= 1) {
        bool desc = ((tid & kk) == 0);
        for (int j = kk >> 1; j; j >>= 1) {
            u64 b;
            if (j >= 64) {
                ov[tid] = a; __syncthreads();
                b = ov[tid ^ j]; __syncthreads();
            } else {
                b = __shfl_xor(a, j);
            }
            bool up = ((tid & j) == 0);
            bool keepMax = (up == desc);
            a = keepMax ? (a > b ? a : b) : (a < b ? a : b);
        }
    }
    ov[tid] = a;
    __syncthreads();
}

// cutoff over 2048-bin hist: K = min(total, KEEP); largest bin cb with count(>=cb) >= K
static __device__ __forceinline__ int cutoff2k(unsigned* hist, unsigned* cs, int tid,
                                               int* s_bin, int* s_K) {
    if (tid == 0) *s_bin = 2048;
    unsigned c = 0;
#pragma unroll
    for (int i = 0; i < 8; i++) c += hist[tid * 8 + i];
    cs[tid] = c;
    __syncthreads();
    for (int d = 1; d < 256; d <<= 1) {
        unsigned v = cs[tid];
        unsigned w = (tid + d < 256) ? cs[tid + d] : 0u;
        __syncthreads();
        cs[tid] = v + w;
        __syncthreads();
    }
    if (tid == 0) *s_K = (int)cs[0] < KEEP ? (int)cs[0] : KEEP;
    __syncthreads();
    int K = *s_K;
    unsigned above = (tid < 255) ? cs[tid + 1] : 0u;
    if (K > 0 && above < (unsigned)K && (unsigned)K <= cs[tid]) {
        unsigned acc = above;
        for (int b = 7; b >= 0; b--) {
            unsigned h = hist[tid * 8 + b];
            if (acc + h >= (unsigned)K) { *s_bin = tid * 8 + b; break; }
            acc += h;
        }
    }
    __syncthreads();
    return *s_bin;
}

// ---------------- launch 1: NMS (7x7 SAME) -> transposed survivor segments ----------------
// also zeroes the launch-2 handshake state each call (deterministic graph replays, no memset)
__global__ void nms_kernel(const float* __restrict__ hm_in, float* __restrict__ hm_out,
                           u64* __restrict__ keys, int* __restrict__ blkcnt, int maxpb,
                           u32* __restrict__ wflags, u32* __restrict__ tag2arr)
{
    const int TX = 64, TY = 16;
    __shared__ float sin_[TY + 6][TX + 6];
    __shared__ float shm[TY + 6][TX];
    __shared__ u64 lkeys[TX * TY];
    __shared__ int lcnt;

    if (blockIdx.x < 4) {
        for (int i = threadIdx.x; i < 1024; i += 256)
            wflags[blockIdx.x * 1024 + i] = 0u;          // whole 16KB flag region
    } else if (blockIdx.x == 4) {
        if (threadIdx.x < NRED) tag2arr[threadIdx.x] = 0u;
    }
    if (threadIdx.x == 0) lcnt = 0;
    int bx = blockIdx.x & 15, by = blockIdx.x >> 4;
    int ox = bx * TX, oy = by * TY;

    for (int i = threadIdx.x; i < (TY + 6) * (TX + 6); i += blockDim.x) {
        int ly = i / (TX + 6), lx = i % (TX + 6);
        int gy = oy + ly - 3, gx = ox + lx - 3;
        float v = 0.f;
        if (gy >= 0 && gy < HH && gx >= 0 && gx < WW) {
            float t = hm_in[gy * WW + gx];
            v = (t > CTHR) ? t : 0.f;
        }
        sin_[ly][lx] = v;
    }
    __syncthreads();
    for (int i = threadIdx.x; i < (TY + 6) * TX; i += blockDim.x) {
        int ly = i / TX, lx = i % TX;
        float m = sin_[ly][lx];
#pragma unroll
        for (int d = 1; d < 7; d++) m = fmaxf(m, sin_[ly][lx + d]);
        shm[ly][lx] = m;
    }
    __syncthreads();
    for (int i = threadIdx.x; i < TY * TX; i += blockDim.x) {
        int ly = i / TX, lx = i % TX;
        float m = shm[ly][lx];
#pragma unroll
        for (int d = 1; d < 7; d++) m = fmaxf(m, shm[ly + d][lx]);
        float c = sin_[ly + 3][lx + 3];
        float o = (m == c) ? c : 0.f;
        int gy = oy + ly, gx = ox + lx;
        hm_out[gy * WW + gx] = o;
        if (o > 0.f) {
            int pos = atomicAdd(&lcnt, 1);      // LDS atomic only
            lkeys[pos] = ((u64)__float_as_uint(o) << 32) |
                         (u64)(0xFFFFFFFFu - (unsigned)(gy * WW + gx));
        }
    }
    __syncthreads();
    int n = lcnt < maxpb ? lcnt : maxpb;
    if (threadIdx.x == 0) blkcnt[blockIdx.x] = n;   // plain store; kernel boundary publishes
    for (int i = threadIdx.x; i < n; i += blockDim.x)
        keys[(size_t)i * NBLK + blockIdx.x] = lkeys[i];
}

// ---------------- launch 2: fused reduce + select + assign (1024 blocks, all resident) -------
// blocks 0-15: reduce own 32 segments (kernel-boundary input, NO waiting) -> release tag2[r]
// block 16:   poll 16 tags -> final select -> centers -> L2 writeback -> 1024 flag words
// all blocks: stage logits tile (hides the select chain), gate on OWN flag (16B stride),
//             tid0 fence, cached center loads, prune + exact assign; 2 tiles each
// smem overlays (33792 B):
//  reduce: kbuf u64[<=4096] @0 (sort overlays dead hist) | hist[2048] @24576 | cs[256] @32768
//  assign: slog[4864] @0 (19456) | sc @19456 (2048) | skept @21504 (2048) | skidx @23552 (512)
__global__ void __launch_bounds__(256) fused_kernel(
        const float* __restrict__ logits, const float* __restrict__ offs,
        const int* __restrict__ thing_ids, int n_thing,
        const u64* __restrict__ keys, const int* __restrict__ blkcnt, int maxpb,
        u64* __restrict__ gtop, u32* __restrict__ gcnt, u32* __restrict__ tag2arr,
        u32* __restrict__ wflags, float4* __restrict__ centers, float* __restrict__ out)
{
    __shared__ __align__(16) char smem[33792];
    __shared__ int scnt2[SEGPB];
    __shared__ int s_m, s_bin, s_K, s_out, s_nkept;
    __shared__ float sred[16];
    __shared__ float ured[4];
    __shared__ int wcnt[4];
    __shared__ int sids[32];

    int bid = blockIdx.x;
    int tid = threadIdx.x, lane = tid & 63, wid = tid >> 6;
    u64 lmask_lt = (1ull << lane) - 1ull;

    if (tid < n_thing) sids[tid] = thing_ids[tid];

    u64* kbuf = (u64*)smem;
    unsigned* hist = (unsigned*)(smem + 24576);
    unsigned* cs   = (unsigned*)(smem + 32768);
    float*  slog  = (float*)smem;
    float4* sc    = (float4*)(smem + 19456);
    float4* skept = (float4*)(smem + 21504);
    int*    skidx = (int*)(smem + 23552);

    float c16x = 0.f, c16y = 0.f, c16z = 0.f, c16w = 0.f;   // block16's center regs

    if (bid < NRED) {
        // ============ reducer r: 32 segments -> <=192 candidates (starts immediately) =========
        int r = bid, g0 = r * SEGPB;
        if (tid < SEGPB) {
            int c = blkcnt[g0 + tid];
            scnt2[tid] = c < 0 ? 0 : (c > maxpb ? maxpb : c);
        }
        if (tid == 0) s_m = 0;
        { uint4* h4 = (uint4*)hist; for (int i = tid; i < 512; i += 256) h4[i] = make_uint4(0,0,0,0); }
        __syncthreads();
        int mxc = 0;
        for (int j = 0; j < SEGPB; j++) { int c = scnt2[j]; mxc = c > mxc ? c : mxc; }
        int nslots = SEGPB * mxc;              // <= 3072

        for (int base = 0; base < nslots; base += 1024) {
            u64 kv[4]; bool pv[4];
#pragma unroll
            for (int u = 0; u < 4; u++) {
                int i = base + u * 256 + tid;
                int sg = i & (SEGPB - 1), sl = i >> 5;
                pv[u] = (i < nslots) && (sl < scnt2[sg]);
                kv[u] = pv[u] ? keys[(size_t)sl * NBLK + (g0 + sg)] : 0ull;
            }
#pragma unroll
            for (int u = 0; u < 4; u++)
                if (pv[u]) atomicAdd(&hist[key_bin2k(kv[u])], 1u);
        }
        __syncthreads();
        int cb = cutoff2k(hist, cs, tid, &s_bin, &s_K);

        for (int base = 0; base < nslots; base += 1024) {
#pragma unroll
            for (int u = 0; u < 4; u++) {
                int i = base + u * 256 + tid;
                int sg = i & (SEGPB - 1), sl = i >> 5;
                bool pv = (i < nslots) && (sl < scnt2[sg]);
                u64 kv = pv ? keys[(size_t)sl * NBLK + (g0 + sg)] : 0ull;
                bool want = pv && key_bin2k(kv) >= cb;
                int pos = lds_push(&s_m, want, lane, lmask_lt);
                if (want) kbuf[pos] = kv;      // pos < 3072
            }
        }
        __syncthreads();
        int n = s_m;
        if (n <= GSLOT) {
            for (int i = tid; i < n; i += 256) gtop[r * GSLOT + i] = kbuf[i];
            if (tid == 0) s_out = n;
        } else {                               // tie-heavy fallback: exact sorted top-128
            int m = 256; while (m < n) m <<= 1;            // <= 4096 (overlays dead hist)
            for (int i = tid; i < m; i += 256) if (i >= n) kbuf[i] = 0ull;
            __syncthreads();
            if (m == 256) bitonic256_reg(kbuf, tid); else bitonic_lds(kbuf, m, tid);
            if (tid < KEEP) gtop[r * GSLOT + tid] = kbuf[tid];
            if (tid == 0) s_out = KEEP;
        }
        __syncthreads();                       // drains vmcnt: gtop writes acked in L2
        if (tid == 0) {
            __hip_atomic_store(&gcnt[r], (u32)s_out, __ATOMIC_RELAXED, __HIP_MEMORY_SCOPE_AGENT);
            __hip_atomic_store(&tag2arr[r], TAGMAGIC, __ATOMIC_RELEASE, __HIP_MEMORY_SCOPE_AGENT);
        }
    } else if (bid == NRED) {
        // ============ final: await 16 tags -> 3072 -> sorted top-128 -> broadcast ============
        if (tid < NRED) {
            while (__hip_atomic_load(&tag2arr[tid], __ATOMIC_RELAXED,
                                     __HIP_MEMORY_SCOPE_AGENT) != TAGMAGIC)
                __builtin_amdgcn_s_sleep(8);   // relaxed poll: no cache-wide ops
        }
        __syncthreads();
        if (tid == 0) __threadfence();         // ONE cache invalidate for the block
        __syncthreads();
        if (tid < NRED) {
            int c = (int)gcnt[tid];
            scnt2[tid] = c < 0 ? 0 : (c > GSLOT ? GSLOT : c);
        }
        if (tid == 0) s_m = 0;
        { uint4* h4 = (uint4*)hist; for (int i = tid; i < 512; i += 256) h4[i] = make_uint4(0,0,0,0); }
        __syncthreads();

        const int nslots = NRED * GSLOT;       // 3072
        for (int base = 0; base < nslots; base += 1024) {
            u64 kv[4]; bool pv[4];
#pragma unroll
            for (int u = 0; u < 4; u++) {
                int i = base + u * 256 + tid;
                int b = i / GSLOT, j = i - b * GSLOT;
                pv[u] = (j < scnt2[b]);
                kv[u] = pv[u] ? gtop[i] : 0ull;
            }
#pragma unroll
            for (int u = 0; u < 4; u++)
                if (pv[u]) atomicAdd(&hist[key_bin2k(kv[u])], 1u);
        }
        __syncthreads();
        int cb = cutoff2k(hist, cs, tid, &s_bin, &s_K);

        for (int base = 0; base < nslots; base += 1024) {
#pragma unroll
            for (int u = 0; u < 4; u++) {
                int i = base + u * 256 + tid;
                int b = i / GSLOT, j = i - b * GSLOT;
                bool pv = (j < scnt2[b]);
                u64 kv = pv ? gtop[i] : 0ull;
                bool want = pv && key_bin2k(kv) >= cb;
                int pos = lds_push(&s_m, want, lane, lmask_lt);
                if (want) kbuf[pos] = kv;
            }
        }
        __syncthreads();
        int n = s_m;
        int m = 256; while (m < n) m <<= 1;    // <= 4096, overlays dead hist
        for (int i = tid; i < m; i += 256) if (i >= n) kbuf[i] = 0ull;
        __syncthreads();
        if (m == 256) bitonic256_reg(kbuf, tid); else bitonic_lds(kbuf, m, tid);

        if (tid < KEEP) {
            u64 k64 = kbuf[tid];
            if (k64 != 0ull) {
                c16w = __uint_as_float((unsigned)(k64 >> 32));
                unsigned idx = 0xFFFFFFFFu - (unsigned)(k64 & 0xFFFFFFFFu);
                c16x = (float)(idx / WW);
                c16y = (float)(idx % WW);
                c16z = c16x * c16x + c16y * c16y;   // exact (< 2^24)
            }
            centers[tid] = make_float4(c16x, c16y, c16z, c16w);
        }
        __syncthreads();                       // vmcnt drained: centers acked in local L2
        if (tid == 0) __threadfence();         // writeback -> coherence point
        __syncthreads();
#pragma unroll
        for (int k = 0; k < 4; k++)            // 1024 flag words, 16B stride (<=4 pollers/line)
            __hip_atomic_store(&wflags[(size_t)(tid + k * 256) * 4], TAGMAGIC,
                               __ATOMIC_RELAXED, __HIP_MEMORY_SCOPE_AGENT);
    }

    // ======================= assign: 2 tiles per block =======================
    for (int j = 0; j < 2; j++) {
        int tile = bid + GRID2 * j;
        __syncthreads();                       // protect smem overlay reuse
        int tbx = tile & 63, tby = tile >> 6;
        int lr = tid >> 4, lc = tid & 15;
        int gy = tby * 16 + lr, gx = tbx * 16 + lc;
        int p = gy * WW + gx;

        {
            const float4* src4 = (const float4*)(logits + ((size_t)(tby * 16) * WW + tbx * 16) * NCLS);
            float4* dst4 = (float4*)slog;
            for (int i = tid; i < 16 * 76; i += 256) {
                int r = i / 76, cidx = i % 76;
                dst4[i] = src4[(size_t)r * 4864 + cidx];
            }
        }

        float2 off2 = ((const float2*)offs)[p];
        float py = __fadd_rn((float)gy, off2.x);
        float px = __fadd_rn((float)gx, off2.y);

        float ymn = py, ymx = py, xmn = px, xmx = px;
        for (int d = 32; d; d >>= 1) {
            ymn = fminf(ymn, __shfl_xor(ymn, d));
            ymx = fmaxf(ymx, __shfl_xor(ymx, d));
            xmn = fminf(xmn, __shfl_xor(xmn, d));
            xmx = fmaxf(xmx, __shfl_xor(xmx, d));
        }
        if (lane == 0) {
            sred[wid * 4 + 0] = ymn; sred[wid * 4 + 1] = ymx;
            sred[wid * 4 + 2] = xmn; sred[wid * 4 + 3] = xmx;
        }

        if (j == 0) {
            // gate on OWN flag word (relaxed; no cache-wide ops), then one fence for the block
            if (tid == 0 && bid != NRED) {
                while (__hip_atomic_load(&wflags[(size_t)bid * 4], __ATOMIC_RELAXED,
                                         __HIP_MEMORY_SCOPE_AGENT) != TAGMAGIC)
                    __builtin_amdgcn_s_sleep(8);
                __threadfence();               // invalidate: centers read fresh below
            }
            __syncthreads();
            if (tid < KEEP) {
                if (bid == NRED) sc[tid] = make_float4(c16x, c16y, c16z, c16w);
                else             sc[tid] = centers[tid];   // normal cached loads (post-fence)
            }
        }
        __syncthreads();                       // sc, sred, slog ready

        float lymn = fminf(fminf(sred[0], sred[4]), fminf(sred[8],  sred[12]));
        float lymx = fmaxf(fmaxf(sred[1], sred[5]), fmaxf(sred[9],  sred[13]));
        float lxmn = fminf(fminf(sred[2], sred[6]), fminf(sred[10], sred[14]));
        float lxmx = fmaxf(fmaxf(sred[3], sred[7]), fmaxf(sred[11], sred[15]));

        float L = INFINITY, U = INFINITY;
        bool valid = false;
        if (tid < KEEP) {
            float4 c4 = sc[tid];
            valid = (c4.w > 0.f);
            if (valid) {
                float dyl = fmaxf(fmaxf(lymn - c4.x, c4.x - lymx), 0.f);
                float dxl = fmaxf(fmaxf(lxmn - c4.y, c4.y - lxmx), 0.f);
                L = dyl * dyl + dxl * dxl;
                float dyu = fmaxf(fabsf(c4.x - lymn), fabsf(c4.x - lymx));
                float dxu = fmaxf(fabsf(c4.y - lxmn), fabsf(c4.y - lxmx));
                U = dyu * dyu + dxu * dxu;
            }
        }
        float u = U;
        for (int d = 32; d; d >>= 1) u = fminf(u, __shfl_xor(u, d));
        if (lane == 0) ured[wid] = u;
        __syncthreads();
        float Umin = fminf(fminf(ured[0], ured[1]), fminf(ured[2], ured[3]));

        bool keep = valid && (L <= Umin + 8.0f);   // margin 8 >> rounding slop ~2
        u64 kmask = __ballot(keep);
        int prefix = __popcll(kmask & lmask_lt);
        if (lane == 0) wcnt[wid] = __popcll(kmask);
        __syncthreads();
        int base = (wid == 1) ? wcnt[0] : 0;
        if (keep) { skept[base + prefix] = sc[tid]; skidx[base + prefix] = tid; }
        if (tid == 0) s_nkept = wcnt[0] + wcnt[1];
        __syncthreads();

        const float* l = slog + tid * NCLS;        // odd stride -> 2-way LDS alias, free
        float best = l[0];
        int cls = 0;
#pragma unroll
        for (int cc = 1; cc < NCLS; cc++) {
            float v = l[cc];
            if (v > best) { best = v; cls = cc; }
        }
        bool thing = false;
        for (int jj = 0; jj < n_thing; jj++) thing = thing || (cls == sids[jj]);

        float b = __fadd_rn(__fmul_rn(py, py), __fmul_rn(px, px));

        float bestd = INFINITY;
        int bi = -1;
        int nk = s_nkept;
        for (int k = 0; k < nk; k++) {
            float4 c4 = skept[k];
            // replicate f32 gemm: m = fma(cx,px, rn(cy*py)); d2 = rn(rn(a-2m)+b)
            float m  = __fmaf_rn(c4.y, px, __fmul_rn(c4.x, py));
            float d2 = __fadd_rn(__fsub_rn(c4.z, __fadd_rn(m, m)), b);
            if (d2 < bestd) { bestd = d2; bi = k; }
        }

        float inst, smap;
        if (bi < 0) { inst = thing ? 1.f : 0.f; smap = 0.f; }
        else {
            inst = thing ? (float)(skidx[bi] + 1) : 0.f;
            smap = thing ? skept[bi].w : 0.f;
        }
        out[p] = inst;
        out[2 * HWSZ + p] = smap;
        out[3 * HWSZ + p] = (float)cls;
    }
}

extern "C" void kernel_launch(void* const* d_in, const int* in_sizes, int n_in,
                              void* d_out, int out_size, void* d_ws, size_t ws_size,
                              hipStream_t stream) {
    const float* logits = (const float*)d_in[0];
    const float* heat   = (const float*)d_in[1];
    const float* offs   = (const float*)d_in[2];
    const int*   tids   = (const int*)d_in[3];
    int n_thing = in_sizes[3];
    if (n_thing > 32) n_thing = 32;

    float* out = (float*)d_out;
    char* ws = (char*)d_ws;
    // layout: tag2arr[16] @0 | gcnt[16] @2048 | blkcnt[512] @4096 (2KB) | centers @8192 (2KB)
    //         wflags[1024*4 u32] @16384 (16KB) | gtop @32768 (24576B) | keys @65536
    u32* tag2arr = (u32*)ws;
    u32* gcnt    = (u32*)(ws + 2048);
    int* blkcnt  = (int*)(ws + 4096);
    float4* centers = (float4*)(ws + 8192);
    u32* wflags  = (u32*)(ws + 16384);
    u64* gtop    = (u64*)(ws + 32768);
    long long avail = (long long)ws_size - 65536;
    int maxpb = (int)(avail / (NBLK * 8));
    if (maxpb > 96) maxpb = 96;    // 32*96 = 3072 = kbuf capacity; true NMS max/tile is 64
    if (maxpb < 16) maxpb = 16;
    u64* keys = (u64*)(ws + 65536);

    nms_kernel<<<dim3(NBLK), dim3(256), 0, stream>>>(heat, out + HWSZ, keys, blkcnt, maxpb,
                                                     wflags, tag2arr);
    fused_kernel<<<dim3(GRID2), dim3(256), 0, stream>>>(
        logits, offs, tids, n_thing, keys, blkcnt, maxpb,
        gtop, gcnt, tag2arr, wflags, centers, out);
}

// Round 18
// 42.563 us; speedup vs baseline: 1.3150x; 1.3150x over previous
//
#include <hip/hip_runtime.h>

#define HH 512
#define WW 1024
#define HWSZ (HH*WW)
#define NCLS 19
#define KEEP 128
#define CTHR 0.1f
#define NBLK 512            // nms tiles = (WW/64)*(HH/16)
#define NRED 16
#define SEGPB 32
#define GSLOT 192
#define TAGMAGIC 0x5A17EC0Du
typedef unsigned int u32;
typedef unsigned long long u64;

// monotone value->bin map, 2048 bins, fine where the data lives (v in [0.5,1))
static __device__ __forceinline__ int key_bin2k(u64 k) {
    unsigned u = (unsigned)(k >> 32);
    if (u >= 0x3F000000u) {
        int b = 1024 + (int)((u - 0x3F000000u) >> 13);
        return b > 2047 ? 2047 : b;
    }
    return (int)(u >> 21);   // < 504
}

// wave-aggregated LDS push; call sites must be wave-uniform
static __device__ __forceinline__ int lds_push(int* cnt, bool want, int lane, u64 lmask_lt) {
    u64 mask = __ballot(want);
    int pos = -1;
    if (mask) {
        int leader = __builtin_ctzll(mask);
        int bpos = 0;
        if (lane == leader) bpos = atomicAdd(cnt, (int)__popcll(mask));
        bpos = __shfl(bpos, leader);
        if (want) pos = bpos + (int)__popcll(mask & lmask_lt);
    }
    return pos;
}

static __device__ __forceinline__ void bitonic_lds(u64* b, int m, int tid) {
    for (int kk = 2; kk <= m; kk <<= 1) {
        for (int j = kk >> 1; j; j >>= 1) {
            for (int i = tid; i < m; i += 256) {
                int ixj = i ^ j;
                if (ixj > i) {
                    bool desc = ((i & kk) == 0);
                    u64 a = b[i], c = b[ixj];
                    if ((a < c) == desc) { b[i] = c; b[ixj] = a; }
                }
            }
            __syncthreads();
        }
    }
}

// 256-elem descending bitonic, 1 elem/thread: shfl for j<64, LDS for j>=64
static __device__ __forceinline__ void bitonic256_reg(u64* ov, int tid) {
    u64 a = ov[tid];
    __syncthreads();
    for (int kk = 2; kk <= 256; kk <<= 1) {
        bool desc = ((tid & kk) == 0);
        for (int j = kk >> 1; j; j >>= 1) {
            u64 b;
            if (j >= 64) {
                ov[tid] = a; __syncthreads();
                b = ov[tid ^ j]; __syncthreads();
            } else {
                b = __shfl_xor(a, j);
            }
            bool up = ((tid & j) == 0);
            bool keepMax = (up == desc);
            a = keepMax ? (a > b ? a : b) : (a < b ? a : b);
        }
    }
    ov[tid] = a;
    __syncthreads();
}

// cutoff over 2048-bin hist: K = min(total, KEEP); largest bin cb with count(>=cb) >= K
static __device__ __forceinline__ int cutoff2k(unsigned* hist, unsigned* cs, int tid,
                                               int* s_bin, int* s_K) {
    if (tid == 0) *s_bin = 2048;
    unsigned c = 0;
#pragma unroll
    for (int i = 0; i < 8; i++) c += hist[tid * 8 + i];
    cs[tid] = c;
    __syncthreads();
    for (int d = 1; d < 256; d <<= 1) {
        unsigned v = cs[tid];
        unsigned w = (tid + d < 256) ? cs[tid + d] : 0u;
        __syncthreads();
        cs[tid] = v + w;
        __syncthreads();
    }
    if (tid == 0) *s_K = (int)cs[0] < KEEP ? (int)cs[0] : KEEP;
    __syncthreads();
    int K = *s_K;
    unsigned above = (tid < 255) ? cs[tid + 1] : 0u;
    if (K > 0 && above < (unsigned)K && (unsigned)K <= cs[tid]) {
        unsigned acc = above;
        for (int b = 7; b >= 0; b--) {
            unsigned h = hist[tid * 8 + b];
            if (acc + h >= (unsigned)K) { *s_bin = tid * 8 + b; break; }
            acc += h;
        }
    }
    __syncthreads();
    return *s_bin;
}

// ---------------- launch 1: NMS (7x7 SAME) -> transposed survivor segments ----------------
__global__ void nms_kernel(const float* __restrict__ hm_in, float* __restrict__ hm_out,
                           u64* __restrict__ keys, int* __restrict__ blkcnt, int maxpb)
{
    const int TX = 64, TY = 16;
    __shared__ float sin_[TY + 6][TX + 6];
    __shared__ float shm[TY + 6][TX];
    __shared__ u64 lkeys[TX * TY];
    __shared__ int lcnt;

    if (threadIdx.x == 0) lcnt = 0;
    int bx = blockIdx.x & 15, by = blockIdx.x >> 4;
    int ox = bx * TX, oy = by * TY;

    for (int i = threadIdx.x; i < (TY + 6) * (TX + 6); i += blockDim.x) {
        int ly = i / (TX + 6), lx = i % (TX + 6);
        int gy = oy + ly - 3, gx = ox + lx - 3;
        float v = 0.f;
        if (gy >= 0 && gy < HH && gx >= 0 && gx < WW) {
            float t = hm_in[gy * WW + gx];
            v = (t > CTHR) ? t : 0.f;
        }
        sin_[ly][lx] = v;
    }
    __syncthreads();
    for (int i = threadIdx.x; i < (TY + 6) * TX; i += blockDim.x) {
        int ly = i / TX, lx = i % TX;
        float m = sin_[ly][lx];
#pragma unroll
        for (int d = 1; d < 7; d++) m = fmaxf(m, sin_[ly][lx + d]);
        shm[ly][lx] = m;
    }
    __syncthreads();
    for (int i = threadIdx.x; i < TY * TX; i += blockDim.x) {
        int ly = i / TX, lx = i % TX;
        float m = shm[ly][lx];
#pragma unroll
        for (int d = 1; d < 7; d++) m = fmaxf(m, shm[ly + d][lx]);
        float c = sin_[ly + 3][lx + 3];
        float o = (m == c) ? c : 0.f;
        int gy = oy + ly, gx = ox + lx;
        hm_out[gy * WW + gx] = o;
        if (o > 0.f) {
            int pos = atomicAdd(&lcnt, 1);      // LDS atomic only
            lkeys[pos] = ((u64)__float_as_uint(o) << 32) |
                         (u64)(0xFFFFFFFFu - (unsigned)(gy * WW + gx));
        }
    }
    __syncthreads();
    int n = lcnt < maxpb ? lcnt : maxpb;
    if (threadIdx.x == 0) blkcnt[blockIdx.x] = n;   // plain store; kernel boundary publishes
    for (int i = threadIdx.x; i < n; i += blockDim.x)
        keys[(size_t)i * NBLK + blockIdx.x] = lkeys[i];
}

// ---------------- launch 2: 17 blocks = 16 reducers (no waiting) + 1 final (single-hop) -----
// smem: kbuf u64[<=4096] @0 (fallback sort overlays hist) | hist[2048] @24576 | cs[256] @32768
__global__ void __launch_bounds__(256) reduce_select_kernel(
        const u64* __restrict__ keys, const int* __restrict__ blkcnt, int maxpb,
        u64* __restrict__ gtop, u32* __restrict__ gcnt, u32* __restrict__ tag2arr,
        float4* __restrict__ centers)
{
    __shared__ __align__(16) char smem[33792];
    __shared__ int scnt2[SEGPB];
    __shared__ int s_m, s_bin, s_K, s_out;

    int tid = threadIdx.x, lane = tid & 63;
    u64 lmask_lt = (1ull << lane) - 1ull;

    u64* kbuf = (u64*)smem;
    unsigned* hist = (unsigned*)(smem + 24576);
    unsigned* cs   = (unsigned*)(smem + 32768);

    if (blockIdx.x < NRED) {
        // ============ reducer r: 32 segments -> <=192 candidates (starts immediately) =========
        int r = blockIdx.x, g0 = r * SEGPB;
        if (tid < SEGPB) {
            int c = blkcnt[g0 + tid];
            scnt2[tid] = c < 0 ? 0 : (c > maxpb ? maxpb : c);
        }
        if (tid == 0) s_m = 0;
        { uint4* h4 = (uint4*)hist; for (int i = tid; i < 512; i += 256) h4[i] = make_uint4(0,0,0,0); }
        __syncthreads();
        int mxc = 0;
        for (int j = 0; j < SEGPB; j++) { int c = scnt2[j]; mxc = c > mxc ? c : mxc; }
        int nslots = SEGPB * mxc;              // <= 3072

        for (int base = 0; base < nslots; base += 1024) {
            u64 kv[4]; bool pv[4];
#pragma unroll
            for (int u = 0; u < 4; u++) {
                int i = base + u * 256 + tid;
                int sg = i & (SEGPB - 1), sl = i >> 5;
                pv[u] = (i < nslots) && (sl < scnt2[sg]);
                kv[u] = pv[u] ? keys[(size_t)sl * NBLK + (g0 + sg)] : 0ull;
            }
#pragma unroll
            for (int u = 0; u < 4; u++)
                if (pv[u]) atomicAdd(&hist[key_bin2k(kv[u])], 1u);
        }
        __syncthreads();
        int cb = cutoff2k(hist, cs, tid, &s_bin, &s_K);

        for (int base = 0; base < nslots; base += 1024) {
#pragma unroll
            for (int u = 0; u < 4; u++) {
                int i = base + u * 256 + tid;
                int sg = i & (SEGPB - 1), sl = i >> 5;
                bool pv = (i < nslots) && (sl < scnt2[sg]);
                u64 kv = pv ? keys[(size_t)sl * NBLK + (g0 + sg)] : 0ull;
                bool want = pv && key_bin2k(kv) >= cb;
                int pos = lds_push(&s_m, want, lane, lmask_lt);
                if (want) kbuf[pos] = kv;      // pos < 3072
            }
        }
        __syncthreads();
        int n = s_m;
        if (n <= GSLOT) {
            for (int i = tid; i < n; i += 256) gtop[r * GSLOT + i] = kbuf[i];
            if (tid == 0) s_out = n;
        } else {                               // tie-heavy fallback: exact sorted top-128
            int m = 256; while (m < n) m <<= 1;            // <= 4096 (overlays dead hist)
            for (int i = tid; i < m; i += 256) if (i >= n) kbuf[i] = 0ull;
            __syncthreads();
            if (m == 256) bitonic256_reg(kbuf, tid); else bitonic_lds(kbuf, m, tid);
            if (tid < KEEP) gtop[r * GSLOT + tid] = kbuf[tid];
            if (tid == 0) s_out = KEEP;
        }
        __syncthreads();                       // drains vmcnt: gtop writes acked in L2
        if (tid == 0) {
            __hip_atomic_store(&gcnt[r], (u32)s_out, __ATOMIC_RELAXED, __HIP_MEMORY_SCOPE_AGENT);
            // RELEASE: one L2 writeback publishes gtop+gcnt, then the tag
            __hip_atomic_store(&tag2arr[r], TAGMAGIC, __ATOMIC_RELEASE, __HIP_MEMORY_SCOPE_AGENT);
        }
        return;
    }

    // ============ final (block 16): await 16 tags -> 3072 -> sorted top-128 ============
    if (tid < NRED) {
        while (__hip_atomic_load(&tag2arr[tid], __ATOMIC_RELAXED,
                                 __HIP_MEMORY_SCOPE_AGENT) != TAGMAGIC)
            __builtin_amdgcn_s_sleep(8);       // relaxed poll: no cache-wide ops (R11/R12)
    }
    __syncthreads();
    if (tid == 0) __threadfence();             // ONE cache invalidate for the block
    __syncthreads();
    if (tid < NRED) {
        int c = (int)gcnt[tid];
        scnt2[tid] = c < 0 ? 0 : (c > GSLOT ? GSLOT : c);
    }
    if (tid == 0) s_m = 0;
    { uint4* h4 = (uint4*)hist; for (int i = tid; i < 512; i += 256) h4[i] = make_uint4(0,0,0,0); }
    __syncthreads();

    const int nslots = NRED * GSLOT;           // 3072
    for (int base = 0; base < nslots; base += 1024) {
        u64 kv[4]; bool pv[4];
#pragma unroll
        for (int u = 0; u < 4; u++) {
            int i = base + u * 256 + tid;
            int b = i / GSLOT, j = i - b * GSLOT;
            pv[u] = (j < scnt2[b]);
            kv[u] = pv[u] ? gtop[i] : 0ull;
        }
#pragma unroll
        for (int u = 0; u < 4; u++)
            if (pv[u]) atomicAdd(&hist[key_bin2k(kv[u])], 1u);
    }
    __syncthreads();
    int cb = cutoff2k(hist, cs, tid, &s_bin, &s_K);

    for (int base = 0; base < nslots; base += 1024) {
#pragma unroll
        for (int u = 0; u < 4; u++) {
            int i = base + u * 256 + tid;
            int b = i / GSLOT, j = i - b * GSLOT;
            bool pv = (j < scnt2[b]);
            u64 kv = pv ? gtop[i] : 0ull;
            bool want = pv && key_bin2k(kv) >= cb;
            int pos = lds_push(&s_m, want, lane, lmask_lt);
            if (want) kbuf[pos] = kv;
        }
    }
    __syncthreads();
    int n = s_m;
    int m = 256; while (m < n) m <<= 1;        // <= 4096, overlays dead hist
    for (int i = tid; i < m; i += 256) if (i >= n) kbuf[i] = 0ull;
    __syncthreads();
    if (m == 256) bitonic256_reg(kbuf, tid); else bitonic_lds(kbuf, m, tid);

    if (tid < KEEP) {
        u64 k64 = kbuf[tid];
        float sc_, cy, cx, a;
        if (k64 == 0ull) { sc_ = 0.f; cy = 0.f; cx = 0.f; a = 0.f; }
        else {
            sc_ = __uint_as_float((unsigned)(k64 >> 32));
            unsigned idx = 0xFFFFFFFFu - (unsigned)(k64 & 0xFFFFFFFFu);
            cy = (float)(idx / WW);
            cx = (float)(idx % WW);
            a = cy * cy + cx * cx;             // exact (< 2^24)
        }
        centers[tid] = make_float4(cy, cx, a, sc_);   // published by kernel boundary
    }
    // reset handshake for next replay (reducers all done; deterministic, no memset node)
    if (tid < NRED)
        __hip_atomic_store(&tag2arr[tid], 0u, __ATOMIC_RELAXED, __HIP_MEMORY_SCOPE_AGENT);
}

// ---------------- launch 3: fused argmax + thing mask + PRUNED nearest-center assignment ------
__global__ void __launch_bounds__(256) assign_kernel(
        const float* __restrict__ logits, const float* __restrict__ offs,
        const int* __restrict__ thing_ids, int n_thing,
        const float4* __restrict__ centers, float* __restrict__ out)
{
    __shared__ float4 sc[KEEP];
    __shared__ float4 skept[KEEP];
    __shared__ int   skidx[KEEP];
    __shared__ float slog[256 * NCLS];
    __shared__ float sred[16];
    __shared__ float ured[4];
    __shared__ int   wcnt[4];
    __shared__ int   s_nkept;
    __shared__ int   sids[32];

    int tid = threadIdx.x;
    if (tid < KEEP) sc[tid] = centers[tid];
    if (tid < n_thing) sids[tid] = thing_ids[tid];

    int bx = blockIdx.x & 63;
    int by = blockIdx.x >> 6;
    int lr = tid >> 4, lc = tid & 15;
    int gy = by * 16 + lr, gx = bx * 16 + lc;
    int p  = gy * WW + gx;

    {
        const float4* src4 = (const float4*)(logits + ((size_t)(by * 16) * WW + bx * 16) * NCLS);
        float4* dst4 = (float4*)slog;
        for (int i = tid; i < 16 * 76; i += 256) {
            int r = i / 76, cidx = i % 76;
            dst4[i] = src4[(size_t)r * 4864 + cidx];
        }
    }

    float2 off2 = ((const float2*)offs)[p];
    float py = __fadd_rn((float)gy, off2.x);
    float px = __fadd_rn((float)gx, off2.y);

    float ymn = py, ymx = py, xmn = px, xmx = px;
    for (int d = 32; d; d >>= 1) {
        ymn = fminf(ymn, __shfl_xor(ymn, d));
        ymx = fmaxf(ymx, __shfl_xor(ymx, d));
        xmn = fminf(xmn, __shfl_xor(xmn, d));
        xmx = fmaxf(xmx, __shfl_xor(xmx, d));
    }
    if ((tid & 63) == 0) {
        int w = tid >> 6;
        sred[w * 4 + 0] = ymn; sred[w * 4 + 1] = ymx;
        sred[w * 4 + 2] = xmn; sred[w * 4 + 3] = xmx;
    }
    __syncthreads();

    ymn = fminf(fminf(sred[0], sred[4]), fminf(sred[8],  sred[12]));
    ymx = fmaxf(fmaxf(sred[1], sred[5]), fmaxf(sred[9],  sred[13]));
    xmn = fminf(fminf(sred[2], sred[6]), fminf(sred[10], sred[14]));
    xmx = fmaxf(fmaxf(sred[3], sred[7]), fmaxf(sred[11], sred[15]));

    float L = INFINITY, U = INFINITY;
    bool valid = false;
    if (tid < KEEP) {
        float4 c4 = sc[tid];
        valid = (c4.w > 0.f);
        if (valid) {
            float dyl = fmaxf(fmaxf(ymn - c4.x, c4.x - ymx), 0.f);
            float dxl = fmaxf(fmaxf(xmn - c4.y, c4.y - xmx), 0.f);
            L = dyl * dyl + dxl * dxl;
            float dyu = fmaxf(fabsf(c4.x - ymn), fabsf(c4.x - ymx));
            float dxu = fmaxf(fabsf(c4.y - xmn), fabsf(c4.y - xmx));
            U = dyu * dyu + dxu * dxu;
        }
    }
    float u = U;
    for (int d = 32; d; d >>= 1) u = fminf(u, __shfl_xor(u, d));
    if ((tid & 63) == 0) ured[tid >> 6] = u;
    __syncthreads();
    float Umin = fminf(fminf(ured[0], ured[1]), fminf(ured[2], ured[3]));

    bool keep = valid && (L <= Umin + 8.0f);   // margin 8 >> rounding slop ~2
    u64 mask = __ballot(keep);
    int lane = tid & 63;
    int prefix = __popcll(mask & ((1ull << lane) - 1ull));
    if (lane == 0) wcnt[tid >> 6] = __popcll(mask);
    __syncthreads();
    int base = (tid >> 6) == 1 ? wcnt[0] : 0;
    if (keep) { skept[base + prefix] = sc[tid]; skidx[base + prefix] = tid; }
    if (tid == 0) s_nkept = wcnt[0] + wcnt[1];
    __syncthreads();

    const float* l = slog + tid * NCLS;        // odd stride -> 2-way LDS alias, free
    float best = l[0];
    int cls = 0;
#pragma unroll
    for (int cc = 1; cc < NCLS; cc++) {
        float v = l[cc];
        if (v > best) { best = v; cls = cc; }
    }
    bool thing = false;
    for (int j = 0; j < n_thing; j++) thing = thing || (cls == sids[j]);

    float b = __fadd_rn(__fmul_rn(py, py), __fmul_rn(px, px));

    float bestd = INFINITY;
    int bi = -1;
    int nk = s_nkept;
    for (int k = 0; k < nk; k++) {
        float4 c4 = skept[k];
        // replicate f32 gemm: m = fma(cx,px, rn(cy*py)); d2 = rn(rn(a-2m)+b)
        float m  = __fmaf_rn(c4.y, px, __fmul_rn(c4.x, py));
        float d2 = __fadd_rn(__fsub_rn(c4.z, __fadd_rn(m, m)), b);
        if (d2 < bestd) { bestd = d2; bi = k; }
    }

    float inst, smap;
    if (bi < 0) { inst = thing ? 1.f : 0.f; smap = 0.f; }
    else {
        inst = thing ? (float)(skidx[bi] + 1) : 0.f;
        smap = thing ? skept[bi].w : 0.f;
    }
    out[p] = inst;
    out[2 * HWSZ + p] = smap;
    out[3 * HWSZ + p] = (float)cls;
}

extern "C" void kernel_launch(void* const* d_in, const int* in_sizes, int n_in,
                              void* d_out, int out_size, void* d_ws, size_t ws_size,
                              hipStream_t stream) {
    const float* logits = (const float*)d_in[0];
    const float* heat   = (const float*)d_in[1];
    const float* offs   = (const float*)d_in[2];
    const int*   tids   = (const int*)d_in[3];
    int n_thing = in_sizes[3];
    if (n_thing > 32) n_thing = 32;

    float* out = (float*)d_out;
    char* ws = (char*)d_ws;
    // layout: tag2arr[16] @0 | gcnt[16] @2048 | blkcnt[512] @4096 (2KB) | centers @8192 (2KB)
    //         gtop @16384 (24576B) | keys @65536 ([maxpb][512])
    u32* tag2arr = (u32*)ws;
    u32* gcnt    = (u32*)(ws + 2048);
    int* blkcnt  = (int*)(ws + 4096);
    float4* centers = (float4*)(ws + 8192);
    u64* gtop = (u64*)(ws + 16384);
    long long avail = (long long)ws_size - 65536;
    int maxpb = (int)(avail / (NBLK * 8));
    if (maxpb > 96) maxpb = 96;    // 32*96 = 3072 = kbuf capacity; true NMS max/tile is 64
    if (maxpb < 16) maxpb = 16;
    u64* keys = (u64*)(ws + 65536);

    nms_kernel<<<dim3(NBLK), dim3(256), 0, stream>>>(heat, out + HWSZ, keys, blkcnt, maxpb);
    reduce_select_kernel<<<dim3(NRED + 1), dim3(256), 0, stream>>>(
        keys, blkcnt, maxpb, gtop, gcnt, tag2arr, centers);
    assign_kernel<<<dim3(2048), dim3(256), 0, stream>>>(
        logits, offs, tids, n_thing, centers, out);
}